// Round 1
// baseline (796.473 us; speedup 1.0000x reference)
//
#include <hip/hip_runtime.h>
#include <math.h>

#define B_ 4
#define T_ 4096
#define C_ 1024
#define D_ 64
#define NROWS (B_ * T_)          // 16384
#define BM 16                    // Q rows per tile
#define BN 64                    // K rows per tile
#define PAD 68                   // LDS row stride (floats), 16B-aligned, breaks pow2 strides

// ---------------------------------------------------------------------------
// Kernel 1: fused QKV projection + RoPE on Q,K.
// Block = 256 threads = 4 waves. Each block handles 16 rows of x.
// Wave w (rg = t>>6) owns rows rg*4..rg*4+3; lane j = t&63 owns output col j.
// x rows held in registers (strided by lane), broadcast per-column via __shfl.
// W streamed from global (L2-resident: 768 KB total, amortized over 16 rows).
// ---------------------------------------------------------------------------
__global__ void qkv_rope_kernel(const float* __restrict__ x,
                                const float* __restrict__ cosp,
                                const float* __restrict__ sinp,
                                const float* __restrict__ Wq,
                                const float* __restrict__ Wk,
                                const float* __restrict__ Wv,
                                float* __restrict__ Qo,
                                float* __restrict__ Ko,
                                float* __restrict__ Vo)
{
    const int t  = threadIdx.x;
    const int j  = t & 63;       // output column / x stride index
    const int rg = t >> 6;       // wave id = row group
    const int row0 = blockIdx.x * 16 + rg * 4;

    // Load 4 x-rows into registers, lane-strided: xr[r][i] = x[row][i*64 + j]
    float xr[4][16];
#pragma unroll
    for (int r = 0; r < 4; ++r) {
        const float* xrow = x + (size_t)(row0 + r) * C_;
#pragma unroll
        for (int i = 0; i < 16; ++i)
            xr[r][i] = xrow[i * 64 + j];
    }

    float aq[4] = {0.f, 0.f, 0.f, 0.f};
    float ak[4] = {0.f, 0.f, 0.f, 0.f};
    float av[4] = {0.f, 0.f, 0.f, 0.f};

#pragma unroll
    for (int i = 0; i < 16; ++i) {
        const float a0 = xr[0][i];
        const float a1 = xr[1][i];
        const float a2 = xr[2][i];
        const float a3 = xr[3][i];
#pragma unroll 8
        for (int l = 0; l < 64; ++l) {
            const int c = i * 64 + l;
            const float wq = Wq[c * 64 + j];
            const float wk = Wk[c * 64 + j];
            const float wv = Wv[c * 64 + j];
            const float x0 = __shfl(a0, l, 64);
            const float x1 = __shfl(a1, l, 64);
            const float x2 = __shfl(a2, l, 64);
            const float x3 = __shfl(a3, l, 64);
            aq[0] = fmaf(x0, wq, aq[0]); ak[0] = fmaf(x0, wk, ak[0]); av[0] = fmaf(x0, wv, av[0]);
            aq[1] = fmaf(x1, wq, aq[1]); ak[1] = fmaf(x1, wk, ak[1]); av[1] = fmaf(x1, wv, av[1]);
            aq[2] = fmaf(x2, wq, aq[2]); ak[2] = fmaf(x2, wk, ak[2]); av[2] = fmaf(x2, wv, av[2]);
            aq[3] = fmaf(x3, wq, aq[3]); ak[3] = fmaf(x3, wk, ak[3]); av[3] = fmaf(x3, wv, av[3]);
        }
    }

    // RoPE on q,k; v passthrough. rot[j] = (j even) ? -val[j+1] : val[j-1]
#pragma unroll
    for (int r = 0; r < 4; ++r) {
        const int g  = row0 + r;
        const int tp = g & (T_ - 1);            // position within sequence
        const float co = cosp[tp * 64 + j];
        const float si = sinp[tp * 64 + j];
        const float q  = aq[r];
        const float k  = ak[r];
        const float qp = __shfl_xor(q, 1, 64);
        const float kp = __shfl_xor(k, 1, 64);
        const float rq = (j & 1) ? qp : -qp;
        const float rk = (j & 1) ? kp : -kp;
        Qo[(size_t)g * D_ + j] = fmaf(q, co, rq * si);
        Ko[(size_t)g * D_ + j] = fmaf(k, co, rk * si);
        Vo[(size_t)g * D_ + j] = av[r];
    }
}

// ---------------------------------------------------------------------------
// Kernel 2: causal flash attention, fp32, online softmax.
// Block = 256 threads = 4 waves; thread: r = t>>4 (row 0..15), o = t&15.
// Thread owns: full Q row in regs (16 float4), S entries s = o+16k (k=0..3),
// O dims [4o, 4o+4).
// Work balance: block p processes Q-tiles p and 255-p (constant total K-tiles).
// Grid = (128, B) = 512 blocks = 2/CU.
// ---------------------------------------------------------------------------
__global__ __launch_bounds__(256) void attn_kernel(const float* __restrict__ Q,
                                                   const float* __restrict__ K,
                                                   const float* __restrict__ V,
                                                   float* __restrict__ out)
{
    __shared__ float Kl[BN][PAD];
    __shared__ float Vl[BN][PAD];
    __shared__ float Pl[BM][PAD];
    __shared__ float Ql[BM][PAD];

    const int t = threadIdx.x;
    const int r = t >> 4;            // row within Q tile
    const int o = t & 15;            // 16-way split of s / d dims
    const int b = blockIdx.y;
    const size_t base = (size_t)b * T_ * D_;

    for (int half = 0; half < 2; ++half) {
        const int qi  = half ? (255 - (int)blockIdx.x) : (int)blockIdx.x;
        const int qr0 = qi * BM;

        // Stage Q tile (16 x 64 floats = 256 float4, one per thread)
        {
            const int row = t >> 4;
            const int c4  = t & 15;
            *(float4*)&Ql[row][c4 * 4] =
                *(const float4*)(Q + base + (size_t)(qr0 + row) * D_ + c4 * 4);
        }
        __syncthreads();

        float4 qv[16];
#pragma unroll
        for (int i = 0; i < 16; ++i)
            qv[i] = *(const float4*)&Ql[r][i * 4];

        float m = -INFINITY;
        float lacc = 0.f;
        float4 oa = make_float4(0.f, 0.f, 0.f, 0.f);

        const int jmax = (qr0 + BM - 1) >> 6;   // last K tile (inclusive)
        for (int kt = 0; kt <= jmax; ++kt) {
            const int kr0 = kt * BN;
            __syncthreads();   // prior PV reads of Kl/Vl done before restaging
#pragma unroll
            for (int u = 0; u < 4; ++u) {
                const int idx = u * 256 + t;
                const int row = idx >> 4;
                const int c4  = idx & 15;
                *(float4*)&Kl[row][c4 * 4] =
                    *(const float4*)(K + base + (size_t)(kr0 + row) * D_ + c4 * 4);
                *(float4*)&Vl[row][c4 * 4] =
                    *(const float4*)(V + base + (size_t)(kr0 + row) * D_ + c4 * 4);
            }
            __syncthreads();

            // S = Q K^T * scale, causal-masked; logits in p[]
            float p[4];
            float mymax = -INFINITY;
#pragma unroll
            for (int k = 0; k < 4; ++k) {
                const int sl = o + 16 * k;
                float dot = 0.f;
#pragma unroll
                for (int d4 = 0; d4 < 16; ++d4) {
                    const float4 kv = *(const float4*)&Kl[sl][d4 * 4];
                    dot = fmaf(qv[d4].x, kv.x, dot);
                    dot = fmaf(qv[d4].y, kv.y, dot);
                    dot = fmaf(qv[d4].z, kv.z, dot);
                    dot = fmaf(qv[d4].w, kv.w, dot);
                }
                dot *= 0.125f;   // HEAD^-0.5
                p[k] = (kr0 + sl <= qr0 + r) ? dot : -INFINITY;
                mymax = fmaxf(mymax, p[k]);
            }
            // row max across the 16 o-threads (lane bits 0..3)
#pragma unroll
            for (int w = 1; w < 16; w <<= 1)
                mymax = fmaxf(mymax, __shfl_xor(mymax, w, 64));

            const float m_new = fmaxf(m, mymax);
            const float alpha = __expf(m - m_new);   // m=-inf first tile -> 0
            float ls = 0.f;
#pragma unroll
            for (int k = 0; k < 4; ++k) {
                p[k] = __expf(p[k] - m_new);         // masked -> exp(-inf)=0
                ls += p[k];
            }
#pragma unroll
            for (int w = 1; w < 16; w <<= 1)
                ls += __shfl_xor(ls, w, 64);

            lacc = lacc * alpha + ls;
            m = m_new;
            oa.x *= alpha; oa.y *= alpha; oa.z *= alpha; oa.w *= alpha;

#pragma unroll
            for (int k = 0; k < 4; ++k)
                Pl[r][o + 16 * k] = p[k];
            __syncthreads();

            // O += P * V  (thread: row r, dims 4o..4o+3)
            for (int sl = 0; sl < BN; ++sl) {
                const float pv = Pl[r][sl];
                const float4 vv = *(const float4*)&Vl[sl][o * 4];
                oa.x = fmaf(pv, vv.x, oa.x);
                oa.y = fmaf(pv, vv.y, oa.y);
                oa.z = fmaf(pv, vv.z, oa.z);
                oa.w = fmaf(pv, vv.w, oa.w);
            }
            __syncthreads();
        }

        const float inv = 1.f / lacc;
        float4 res;
        res.x = oa.x * inv; res.y = oa.y * inv;
        res.z = oa.z * inv; res.w = oa.w * inv;
        *(float4*)(out + base + (size_t)(qr0 + r) * D_ + o * 4) = res;
        __syncthreads();   // Ql restage next half
    }
}

extern "C" void kernel_launch(void* const* d_in, const int* in_sizes, int n_in,
                              void* d_out, int out_size, void* d_ws, size_t ws_size,
                              hipStream_t stream)
{
    const float* x    = (const float*)d_in[0];
    const float* cosp = (const float*)d_in[1];
    const float* sinp = (const float*)d_in[2];
    // d_in[3] = tril: unused (causality is structural)
    const float* Wq   = (const float*)d_in[4];
    const float* Wk   = (const float*)d_in[5];
    const float* Wv   = (const float*)d_in[6];
    float* out = (float*)d_out;

    float* Qw = (float*)d_ws;                      // 16384 x 64
    float* Kw = Qw + (size_t)NROWS * D_;
    float* Vw = Kw + (size_t)NROWS * D_;

    qkv_rope_kernel<<<NROWS / 16, 256, 0, stream>>>(x, cosp, sinp, Wq, Wk, Wv,
                                                    Qw, Kw, Vw);
    attn_kernel<<<dim3(T_ / BM / 2, B_), 256, 0, stream>>>(Qw, Kw, Vw, out);
}

// Round 2
// 288.919 us; speedup vs baseline: 2.7567x; 2.7567x over previous
//
#include <hip/hip_runtime.h>
#include <math.h>

#define T_ 4096
#define NROWS 16384            // B*T

typedef __attribute__((ext_vector_type(8))) short short8;   // 8 bf16
typedef __attribute__((ext_vector_type(4))) short short4v;  // 4 bf16
typedef __attribute__((ext_vector_type(4))) float float4v;

#define MFMA(a, b, c) __builtin_amdgcn_mfma_f32_16x16x32_bf16((a), (b), (c), 0, 0, 0)

__device__ __forceinline__ short f2bf(float f) {
    unsigned u = __builtin_bit_cast(unsigned, f);
    u += 0x7fffu + ((u >> 16) & 1u);          // RNE truncate to bf16
    return (short)(u >> 16);
}

// ---------------------------------------------------------------------------
// Kernel 0: weights fp32 (C x 64) -> Wt bf16 [192][1024], Wt[n][k] = W[k][n].
// Rows 0..63 = Wq^T, 64..127 = Wk^T, 128..191 = Wv^T.
// ---------------------------------------------------------------------------
__global__ void wprep_kernel(const float* __restrict__ Wq,
                             const float* __restrict__ Wk,
                             const float* __restrict__ Wv,
                             short* __restrict__ Wt)
{
    const int n  = blockIdx.x;            // 0..191
    const int k0 = threadIdx.x * 4;       // 256 thr * 4 = 1024
    const float* W = (n < 64) ? Wq : (n < 128) ? Wk : Wv;
    const int c = n & 63;
    short4v o;
#pragma unroll
    for (int i = 0; i < 4; ++i) o[i] = f2bf(W[(size_t)(k0 + i) * 64 + c]);
    *(short4v*)(Wt + (size_t)n * 1024 + k0) = o;
}

// ---------------------------------------------------------------------------
// Kernel 1: MFMA QKV projection + fused RoPE.
// Block 256 = 4 waves; wave owns 16 rows, all 12 n-tiles (q:0-3 k:4-7 v:8-11).
// A-frag: lane m=lane&15 reads x[row][it*32+quad*8+j] (2 float4, cvt bf16).
// B-frag: Wt[nt*16+ln][it*32+quad*8 ..+7] contiguous 16B.
// Epilogue: RoPE on q,k (pair = shfl_xor 1, cols live in lane&15), store
// Q,K bf16 row-major; V stored in attention's B-fragment swizzled layout
// (4 packed short4 stores per lane, coalesced).
// ---------------------------------------------------------------------------
__global__ __launch_bounds__(256) void qkv_kernel(
    const float* __restrict__ x, const float* __restrict__ cosp,
    const float* __restrict__ sinp, const short* __restrict__ Wt,
    short* __restrict__ Qb, short* __restrict__ Kb, short* __restrict__ Vs)
{
    const int t = threadIdx.x;
    const int w = t >> 6, lane = t & 63;
    const int ln = lane & 15, quad = lane >> 4;
    const int rb = blockIdx.x * 64 + w * 16;

    const float* xp = x + (size_t)(rb + ln) * 1024 + quad * 8;

    float4v acc[12];
#pragma unroll
    for (int i = 0; i < 12; ++i) acc[i] = (float4v){0.f, 0.f, 0.f, 0.f};

    for (int it = 0; it < 32; ++it) {
        const float4 xa = *(const float4*)(xp + it * 32);
        const float4 xb = *(const float4*)(xp + it * 32 + 4);
        short8 a;
        a[0] = f2bf(xa.x); a[1] = f2bf(xa.y); a[2] = f2bf(xa.z); a[3] = f2bf(xa.w);
        a[4] = f2bf(xb.x); a[5] = f2bf(xb.y); a[6] = f2bf(xb.z); a[7] = f2bf(xb.w);
#pragma unroll
        for (int nt = 0; nt < 12; ++nt) {
            const short8 bf = *(const short8*)(Wt + (size_t)(nt * 16 + ln) * 1024 + it * 32 + quad * 8);
            acc[nt] = MFMA(a, bf, acc[nt]);
        }
    }

    // ---- RoPE + store Q,K (row-major bf16) ----
#pragma unroll
    for (int reg = 0; reg < 4; ++reg) {
        const int g  = rb + quad * 4 + reg;        // global row (incl. batch)
        const int tp = g & (T_ - 1);               // position in sequence
#pragma unroll
        for (int nt = 0; nt < 4; ++nt) {
            const int j = nt * 16 + ln;
            const float cv = cosp[(size_t)tp * 64 + j];
            const float sv = sinp[(size_t)tp * 64 + j];
            const float q  = acc[nt][reg];
            const float k  = acc[nt + 4][reg];
            const float qp = __shfl_xor(q, 1, 64);
            const float kp = __shfl_xor(k, 1, 64);
            const float rq = (ln & 1) ? qp : -qp;
            const float rk = (ln & 1) ? kp : -kp;
            Qb[(size_t)g * 64 + j] = f2bf(fmaf(q, cv, rq * sv));
            Kb[(size_t)g * 64 + j] = f2bf(fmaf(k, cv, rk * sv));
        }
    }

    // ---- V in swizzled B-fragment layout ----
    // slot[(b*64+kt)*8 + nt*2 + h][lane'=qd*16+ln][j] = V[kt*64+32h+8qd+j][nt*16+ln]
    const int b  = rb >> 12;
    const int kt = (rb & (T_ - 1)) >> 6;
    const int h  = w >> 1;
    const int qd = (w & 1) * 2 + (quad >> 1);
    const int jb = (quad & 1) * 4;                 // reg 0..3 -> j = jb+reg
#pragma unroll
    for (int nt = 0; nt < 4; ++nt) {
        short4v pv;
#pragma unroll
        for (int reg = 0; reg < 4; ++reg) pv[reg] = f2bf(acc[nt + 8][reg]);
        const size_t addr =
            (((size_t)(b * 64 + kt) * 8 + nt * 2 + h) * 64 + qd * 16 + ln) * 8 + jb;
        *(short4v*)(Vs + addr) = pv;
    }
}

// ---------------------------------------------------------------------------
// Kernel 2: MFMA flash attention. One wave per block (64 thr), 16 Q-rows,
// BN=64 K-tiles, online softmax in C-layout (row = quad*4+reg, col = lane&15).
// No barriers: K/V frags load straight from global in MFMA layout; P goes
// C-layout -> A-layout through a private 16x72-bf16 LDS tile (2-way banks).
// Register double-buffer prefetches tile kt+1. Pair (qi, 255-qi) balances.
// ---------------------------------------------------------------------------
#define LOADKV(kf, vf, ktv)                                                    \
    {                                                                          \
        const int _kt = (ktv);                                                 \
        const short* _kb = Kp + (size_t)_kt * 4096;                            \
        const short* _vb = Vp + (size_t)_kt * 4096 + lane * 8;                 \
        _Pragma("unroll")                                                      \
        for (int nt = 0; nt < 4; ++nt) {                                       \
            _Pragma("unroll")                                                  \
            for (int hh = 0; hh < 2; ++hh) {                                   \
                kf[nt * 2 + hh] = *(const short8*)(_kb + (nt * 16 + ln) * 64 + quad * 8 + hh * 32); \
                vf[nt * 2 + hh] = *(const short8*)(_vb + (nt * 2 + hh) * 512); \
            }                                                                  \
        }                                                                      \
    }

#define STEP(ktv, kf, vf)                                                      \
    {                                                                          \
        const int _kt = (ktv);                                                 \
        float4v s[4];                                                          \
        _Pragma("unroll")                                                      \
        for (int nt = 0; nt < 4; ++nt) {                                       \
            s[nt] = (float4v){0.f, 0.f, 0.f, 0.f};                             \
            s[nt] = MFMA(aq0, kf[nt * 2], s[nt]);                              \
            s[nt] = MFMA(aq1, kf[nt * 2 + 1], s[nt]);                          \
        }                                                                      \
        const int _colb = _kt * 64 + ln;                                       \
        const int _rowb = qr0 + quad * 4;                                      \
        _Pragma("unroll")                                                      \
        for (int nt = 0; nt < 4; ++nt) {                                       \
            _Pragma("unroll")                                                  \
            for (int r = 0; r < 4; ++r)                                        \
                s[nt][r] = (_colb + nt * 16 <= _rowb + r) ? s[nt][r] * 0.125f  \
                                                          : -__builtin_inff(); \
        }                                                                      \
        float4v rm;                                                            \
        _Pragma("unroll")                                                      \
        for (int r = 0; r < 4; ++r)                                            \
            rm[r] = fmaxf(fmaxf(s[0][r], s[1][r]), fmaxf(s[2][r], s[3][r]));   \
        _Pragma("unroll")                                                      \
        for (int r = 0; r < 4; ++r) {                                          \
            float v = rm[r];                                                   \
            v = fmaxf(v, __shfl_xor(v, 1, 64));                                \
            v = fmaxf(v, __shfl_xor(v, 2, 64));                                \
            v = fmaxf(v, __shfl_xor(v, 4, 64));                                \
            v = fmaxf(v, __shfl_xor(v, 8, 64));                                \
            const float mn = fmaxf(m[r], v);                                   \
            const float al = __expf(m[r] - mn);                                \
            float ls = 0.f;                                                    \
            _Pragma("unroll")                                                  \
            for (int nt = 0; nt < 4; ++nt) {                                   \
                const float pv = __expf(s[nt][r] - mn);                        \
                s[nt][r] = pv;                                                 \
                ls += pv;                                                      \
            }                                                                  \
            ls += __shfl_xor(ls, 1, 64);                                       \
            ls += __shfl_xor(ls, 2, 64);                                       \
            ls += __shfl_xor(ls, 4, 64);                                       \
            ls += __shfl_xor(ls, 8, 64);                                       \
            l[r] = l[r] * al + ls;                                             \
            m[r] = mn;                                                         \
            _Pragma("unroll")                                                  \
            for (int nt = 0; nt < 4; ++nt) o[nt][r] *= al;                     \
        }                                                                      \
        _Pragma("unroll")                                                      \
        for (int nt = 0; nt < 4; ++nt) {                                       \
            _Pragma("unroll")                                                  \
            for (int r = 0; r < 4; ++r)                                        \
                pw[(quad * 4 + r) * 72 + nt * 16 + ln] = f2bf(s[nt][r]);       \
        }                                                                      \
        const short8 ap0 = *(const short8*)(pw + ln * 72 + quad * 8);          \
        const short8 ap1 = *(const short8*)(pw + ln * 72 + quad * 8 + 32);     \
        _Pragma("unroll")                                                      \
        for (int nt = 0; nt < 4; ++nt) {                                       \
            o[nt] = MFMA(ap0, vf[nt * 2], o[nt]);                              \
            o[nt] = MFMA(ap1, vf[nt * 2 + 1], o[nt]);                          \
        }                                                                      \
    }

__global__ __launch_bounds__(64) void attn_kernel(
    const short* __restrict__ Qb, const short* __restrict__ Kb,
    const short* __restrict__ Vs, float* __restrict__ out)
{
    __shared__ __align__(16) short Pl[16 * 72];
    const int lane = threadIdx.x;
    const int ln = lane & 15, quad = lane >> 4;
    short* pw = Pl;
    const int b = blockIdx.y;
    const short* Qp = Qb + (size_t)b * T_ * 64;
    const short* Kp = Kb + (size_t)b * T_ * 64;
    const short* Vp = Vs + (size_t)b * T_ * 64;
    float* op = out + (size_t)b * T_ * 64;

    for (int job = 0; job < 2; ++job) {
        int qi = blockIdx.x;                 // 0..127
        if (job) qi = 255 - qi;              // 128..255
        const int qr0 = qi * 16;

        const short8 aq0 = *(const short8*)(Qp + (size_t)(qr0 + ln) * 64 + quad * 8);
        const short8 aq1 = *(const short8*)(Qp + (size_t)(qr0 + ln) * 64 + quad * 8 + 32);

        float4v m = { -__builtin_inff(), -__builtin_inff(), -__builtin_inff(), -__builtin_inff() };
        float4v l = { 0.f, 0.f, 0.f, 0.f };
        float4v o[4];
#pragma unroll
        for (int i = 0; i < 4; ++i) o[i] = (float4v){0.f, 0.f, 0.f, 0.f};

        const int ktend = qr0 >> 6;
        short8 k0f[8], v0f[8], k1f[8], v1f[8];

        LOADKV(k0f, v0f, 0);
        for (int kt = 0; kt <= ktend; kt += 2) {
            const bool h1 = (kt + 1) <= ktend;
            if (h1) LOADKV(k1f, v1f, kt + 1);
            STEP(kt, k0f, v0f);
            if (h1) {
                if (kt + 2 <= ktend) LOADKV(k0f, v0f, kt + 2);
                STEP(kt + 1, k1f, v1f);
            }
        }

#pragma unroll
        for (int r = 0; r < 4; ++r) {
            const float inv = 1.0f / l[r];
            const int g = qr0 + quad * 4 + r;
#pragma unroll
            for (int nt = 0; nt < 4; ++nt)
                op[(size_t)g * 64 + nt * 16 + ln] = o[nt][r] * inv;
        }
    }
}

extern "C" void kernel_launch(void* const* d_in, const int* in_sizes, int n_in,
                              void* d_out, int out_size, void* d_ws, size_t ws_size,
                              hipStream_t stream)
{
    const float* x    = (const float*)d_in[0];
    const float* cosp = (const float*)d_in[1];
    const float* sinp = (const float*)d_in[2];
    // d_in[3] = tril: unused (causality structural)
    const float* Wq   = (const float*)d_in[4];
    const float* Wk   = (const float*)d_in[5];
    const float* Wv   = (const float*)d_in[6];
    float* out = (float*)d_out;

    short* Qb = (short*)d_ws;                 // 16384*64 bf16
    short* Kb = Qb + (size_t)NROWS * 64;
    short* Vs = Kb + (size_t)NROWS * 64;      // swizzled V, same size
    short* Wt = Vs + (size_t)NROWS * 64;      // 192*1024 bf16

    wprep_kernel<<<192, 256, 0, stream>>>(Wq, Wk, Wv, Wt);
    qkv_kernel<<<NROWS / 64, 256, 0, stream>>>(x, cosp, sinp, Wt, Qb, Kb, Vs);
    attn_kernel<<<dim3(128, 4), 64, 0, stream>>>(Qb, Kb, Vs, out);
}

// Round 3
// 211.054 us; speedup vs baseline: 3.7738x; 1.3689x over previous
//
#include <hip/hip_runtime.h>
#include <math.h>

#define T_ 4096
#define NROWS 16384            // B*T

typedef __attribute__((ext_vector_type(8))) short short8;   // 8 bf16
typedef __attribute__((ext_vector_type(4))) short short4v;  // 4 bf16
typedef __attribute__((ext_vector_type(4))) float float4v;
typedef __attribute__((ext_vector_type(2))) unsigned uint2v;

#define MFMA(a, b, c) __builtin_amdgcn_mfma_f32_16x16x32_bf16((a), (b), (c), 0, 0, 0)

#if defined(__has_builtin)
#if __has_builtin(__builtin_amdgcn_exp2f)
#define EXP2(x) __builtin_amdgcn_exp2f(x)
#else
#define EXP2(x) exp2f(x)
#endif
#else
#define EXP2(x) exp2f(x)
#endif

#define SCALE_Q 0.18033688011112042f   // 0.125 * log2(e), folded into Q

__device__ __forceinline__ short f2bf(float f) {
    unsigned u = __builtin_bit_cast(unsigned, f);
    u += 0x7fffu + ((u >> 16) & 1u);          // RNE truncate to bf16
    return (short)(u >> 16);
}
__device__ __forceinline__ unsigned pack_bf2(float a, float b) {
    unsigned ua = __builtin_bit_cast(unsigned, a);
    unsigned ub = __builtin_bit_cast(unsigned, b);
    ua += 0x7fffu + ((ua >> 16) & 1u);
    ub += 0x7fffu + ((ub >> 16) & 1u);
    return (ua >> 16) | (ub & 0xffff0000u);
}

// ---------------------------------------------------------------------------
// Kernel 0: weights fp32 (C x 64) -> Wt bf16 [192][1024], Wt[n][k] = W[k][n].
// ---------------------------------------------------------------------------
__global__ void wprep_kernel(const float* __restrict__ Wq,
                             const float* __restrict__ Wk,
                             const float* __restrict__ Wv,
                             short* __restrict__ Wt)
{
    const int n  = blockIdx.x;            // 0..191
    const int k0 = threadIdx.x * 4;
    const float* W = (n < 64) ? Wq : (n < 128) ? Wk : Wv;
    const int c = n & 63;
    short4v o;
#pragma unroll
    for (int i = 0; i < 4; ++i) o[i] = f2bf(W[(size_t)(k0 + i) * 64 + c]);
    *(short4v*)(Wt + (size_t)n * 1024 + k0) = o;
}

// ---------------------------------------------------------------------------
// Kernel 1: MFMA QKV projection + fused RoPE, LDS-staged.
// Block 256 thr / 4 waves / 64 rows. K staged in 8 chunks of 128.
// LDS frag-major: WL[it4][nt12][lane64][8], XL[it4][af4][lane64][8] (64 KB).
// Wave w computes all 64 rows (af 0..3) x nt = 3w..3w+2 -> 12 acc tiles.
// W read once per BLOCK (vs per wave before): 16x less L2 traffic.
// Epilogue: RoPE on q,k (Q scaled by 0.125*log2e for exp2 softmax);
// V stored in attention's B-fragment swizzled layout.
// ---------------------------------------------------------------------------
__global__ __launch_bounds__(256) void qkv_kernel(
    const float* __restrict__ x, const float* __restrict__ cosp,
    const float* __restrict__ sinp, const short* __restrict__ Wt,
    short* __restrict__ Qb, short* __restrict__ Kb, short* __restrict__ Vs)
{
    __shared__ short WL[24576];   // 48 KB
    __shared__ short XL[8192];    // 16 KB

    const int t = threadIdx.x;
    const int w = t >> 6, lane = t & 63;
    const int ln = lane & 15, quad = lane >> 4;
    const int rb = blockIdx.x * 64;

    // staging decode (constant per thread)
    const int wq  = t & 3, wit = (t >> 2) & 3, wln = t >> 4;           // W: nt = j
    const int xh  = t & 1, xq = (t >> 1) & 3, xit = (t >> 3) & 3;
    const int xr0 = t >> 5;                                            // x: rowi = j*8+xr0

    float4 xr[8];
    short8 wr[12];
    float4v acc[4][3];
#pragma unroll
    for (int i = 0; i < 4; ++i)
#pragma unroll
        for (int j = 0; j < 3; ++j) acc[i][j] = (float4v){0.f, 0.f, 0.f, 0.f};

#define LOAD_CHUNK(c)                                                          \
    {   const int _k0 = (c) * 128;                                             \
        _Pragma("unroll")                                                      \
        for (int j = 0; j < 12; ++j)                                           \
            wr[j] = *(const short8*)(Wt + (size_t)(j * 16 + wln) * 1024 + _k0  \
                                        + wit * 32 + wq * 8);                  \
        _Pragma("unroll")                                                      \
        for (int j = 0; j < 8; ++j) {                                          \
            const int rowi = j * 8 + xr0;                                      \
            xr[j] = *(const float4*)(x + (size_t)(rb + rowi) * 1024 + _k0      \
                                       + xit * 32 + xq * 8 + xh * 4);          \
        } }

#define WRITE_CHUNK()                                                          \
    {   _Pragma("unroll")                                                      \
        for (int j = 0; j < 12; ++j)                                           \
            *(short8*)(WL + ((wit * 12 + j) * 64 + wq * 16 + wln) * 8) = wr[j];\
        _Pragma("unroll")                                                      \
        for (int j = 0; j < 8; ++j) {                                          \
            const int rowi = j * 8 + xr0;                                      \
            const int af = rowi >> 4, lnx = rowi & 15;                         \
            short4v v;                                                         \
            v[0] = f2bf(xr[j].x); v[1] = f2bf(xr[j].y);                        \
            v[2] = f2bf(xr[j].z); v[3] = f2bf(xr[j].w);                        \
            *(short4v*)(XL + ((xit * 4 + af) * 64 + xq * 16 + lnx) * 8 + xh * 4) = v; \
        } }

    LOAD_CHUNK(0)
    for (int c = 0; c < 8; ++c) {
        __syncthreads();               // prior chunk's LDS reads complete
        WRITE_CHUNK()
        __syncthreads();
        if (c < 7) LOAD_CHUNK(c + 1)   // overlap next global loads with compute
#pragma unroll
        for (int it = 0; it < 4; ++it) {
            short8 a[4], bf[3];
#pragma unroll
            for (int af = 0; af < 4; ++af)
                a[af] = *(const short8*)(XL + ((it * 4 + af) * 64 + lane) * 8);
#pragma unroll
            for (int j = 0; j < 3; ++j)
                bf[j] = *(const short8*)(WL + ((it * 12 + w * 3 + j) * 64 + lane) * 8);
#pragma unroll
            for (int af = 0; af < 4; ++af)
#pragma unroll
                for (int j = 0; j < 3; ++j)
                    acc[af][j] = MFMA(a[af], bf[j], acc[af][j]);
        }
    }

    // ---- epilogue ----
    const int b  = rb >> 12;
    const int kt = (rb & (T_ - 1)) >> 6;
#pragma unroll
    for (int j = 0; j < 3; ++j) {
        const int nt = w * 3 + j;
        if (nt < 8) {                          // Q (0..3) or K (4..7) + RoPE
            const bool isq = nt < 4;
            const int col = (isq ? nt : nt - 4) * 16 + ln;
            short* dst = isq ? Qb : Kb;
#pragma unroll
            for (int af = 0; af < 4; ++af) {
#pragma unroll
                for (int reg = 0; reg < 4; ++reg) {
                    const int g  = rb + af * 16 + quad * 4 + reg;
                    const int tp = g & (T_ - 1);
                    const float cv = cosp[(size_t)tp * 64 + col];
                    const float sv = sinp[(size_t)tp * 64 + col];
                    const float v  = acc[af][j][reg];
                    const float vp = __shfl_xor(v, 1, 64);
                    const float rot = (ln & 1) ? vp : -vp;
                    float res = fmaf(v, cv, rot * sv);
                    if (isq) res *= SCALE_Q;
                    dst[(size_t)g * 64 + col] = f2bf(res);
                }
            }
        } else {                               // V -> swizzled B-frag layout
            const int vnt = nt - 8;
#pragma unroll
            for (int af = 0; af < 4; ++af) {
                const int hh = af >> 1;
                const int qp = (af & 1) * 2 + (quad >> 1);
                const int jb = (quad & 1) * 4;
                short4v pv;
#pragma unroll
                for (int reg = 0; reg < 4; ++reg) pv[reg] = f2bf(acc[af][j][reg]);
                const size_t addr =
                    ((((size_t)(b * 64 + kt) * 4 + vnt) * 2 + hh) * 64 + qp * 16 + ln) * 8 + jb;
                *(short4v*)(Vs + addr) = pv;
            }
        }
    }
}

// ---------------------------------------------------------------------------
// Kernel 2: MFMA flash attention, 4-way split-K per Q-tile.
// Block 256 thr / 4 waves; wave w owns K-tiles kt = w, w+4, ... with private
// online-softmax state (S^T orientation: stats are per-lane scalars,
// reductions = 2 shfls). Grid (256,4), qi = 255-bx (big tiles first).
// Partial (m,l,o) merged once through LDS at the end.
// ---------------------------------------------------------------------------
#define LOADK(kf, ktv)                                                         \
    {   const short* _kb = Kp + (size_t)(ktv) * 4096;                          \
        _Pragma("unroll")                                                      \
        for (int st = 0; st < 4; ++st)                                         \
            _Pragma("unroll")                                                  \
            for (int h = 0; h < 2; ++h)                                        \
                kf[st * 2 + h] = *(const short8*)(_kb + (st * 16 + ln) * 64 + quad * 8 + h * 32); }

#define LOADV(vfb, ktv)                                                        \
    {   const short* _vb = Vp + (size_t)(ktv) * 4096 + lane * 8;               \
        _Pragma("unroll")                                                      \
        for (int u = 0; u < 8; ++u) vfb[u] = *(const short8*)(_vb + u * 512); }

#define STEP(ktv, kf, vfb, masked)                                             \
    {   float4v s[4];                                                          \
        _Pragma("unroll")                                                      \
        for (int st = 0; st < 4; ++st) {                                       \
            s[st] = (float4v){0.f, 0.f, 0.f, 0.f};                             \
            s[st] = MFMA(kf[st * 2],     qb0, s[st]);   /* S^T = K*Q^T */      \
            s[st] = MFMA(kf[st * 2 + 1], qb1, s[st]);                          \
        }                                                                      \
        if (masked) {                                                          \
            _Pragma("unroll")                                                  \
            for (int st = 0; st < 4; ++st)                                     \
                _Pragma("unroll")                                              \
                for (int r = 0; r < 4; ++r)                                    \
                    if ((ktv) * 64 + st * 16 + quad * 4 + r > qr0 + ln)        \
                        s[st][r] = -__builtin_inff();                          \
        }                                                                      \
        float mx = s[0][0];                                                    \
        _Pragma("unroll")                                                      \
        for (int st = 0; st < 4; ++st)                                         \
            _Pragma("unroll")                                                  \
            for (int r = 0; r < 4; ++r) mx = fmaxf(mx, s[st][r]);              \
        mx = fmaxf(mx, __shfl_xor(mx, 16, 64));                                \
        mx = fmaxf(mx, __shfl_xor(mx, 32, 64));                                \
        const float mn = fmaxf(m, mx);                                         \
        const float al = EXP2(m - mn);                                         \
        float ls = 0.f;                                                        \
        _Pragma("unroll")                                                      \
        for (int st = 0; st < 4; ++st)                                         \
            _Pragma("unroll")                                                  \
            for (int r = 0; r < 4; ++r) {                                      \
                const float p = EXP2(s[st][r] - mn);                           \
                s[st][r] = p; ls += p;                                         \
            }                                                                  \
        ls += __shfl_xor(ls, 16, 64);                                          \
        ls += __shfl_xor(ls, 32, 64);                                          \
        l = l * al + ls; m = mn;                                               \
        float alr[4];                                                          \
        _Pragma("unroll")                                                      \
        for (int r = 0; r < 4; ++r) alr[r] = __shfl(al, quad * 4 + r, 64);     \
        _Pragma("unroll")                                                      \
        for (int vn = 0; vn < 4; ++vn)                                         \
            _Pragma("unroll")                                                  \
            for (int r = 0; r < 4; ++r) o[vn][r] *= alr[r];                    \
        _Pragma("unroll")                                                      \
        for (int st = 0; st < 4; ++st) {                                       \
            uint2v pk;                                                         \
            pk[0] = pack_bf2(s[st][0], s[st][1]);                              \
            pk[1] = pack_bf2(s[st][2], s[st][3]);                              \
            *(uint2v*)(pw + ln * 104 + st * 16 + quad * 4) = pk;               \
        }                                                                      \
        const short8 ap0 = *(const short8*)(pw + ln * 104 + quad * 8);         \
        const short8 ap1 = *(const short8*)(pw + ln * 104 + quad * 8 + 32);    \
        _Pragma("unroll")                                                      \
        for (int vn = 0; vn < 4; ++vn) {                                       \
            o[vn] = MFMA(ap0, vfb[vn * 2],     o[vn]);                         \
            o[vn] = MFMA(ap1, vfb[vn * 2 + 1], o[vn]);                         \
        }                                                                      \
    }

__global__ __launch_bounds__(256, 3) void attn_kernel(
    const short* __restrict__ Qb, const short* __restrict__ Kb,
    const short* __restrict__ Vs, float* __restrict__ out)
{
    __shared__ __align__(16) short PLs[4][16 * 104];  // per-wave P tile
    __shared__ float OL[4][16][68];
    __shared__ float SMm[4][16];
    __shared__ float SLl[4][16];

    const int t = threadIdx.x, w = t >> 6, lane = t & 63;
    const int ln = lane & 15, quad = lane >> 4;
    const int b = blockIdx.y;
    const int qi = 255 - (int)blockIdx.x;     // big tiles dispatched first
    const int qr0 = qi * 16;
    const short* Qp = Qb + (size_t)b * T_ * 64;
    const short* Kp = Kb + (size_t)b * T_ * 64;
    const short* Vp = Vs + (size_t)b * T_ * 64;
    short* pw = PLs[w];

    // Q as B-operand (already scaled by 0.125*log2e in qkv epilogue)
    const short8 qb0 = *(const short8*)(Qp + (size_t)(qr0 + ln) * 64 + quad * 8);
    const short8 qb1 = *(const short8*)(Qp + (size_t)(qr0 + ln) * 64 + quad * 8 + 32);

    float m = -__builtin_inff(), l = 0.f;
    float4v o[4];
#pragma unroll
    for (int i = 0; i < 4; ++i) o[i] = (float4v){0.f, 0.f, 0.f, 0.f};

    const int ktend = qi >> 2;
    short8 k0f[8], k1f[8], vfb[8];

    int kt = w;
    if (kt <= ktend) {
        LOADK(k0f, kt)
        while (true) {
            LOADV(vfb, kt)
            {
                const bool more = (kt + 4) <= ktend;
                if (more) LOADK(k1f, kt + 4)
                STEP(kt, k0f, vfb, kt == ktend)
                kt += 4;
                if (!more) break;
            }
            LOADV(vfb, kt)
            {
                const bool more = (kt + 4) <= ktend;
                if (more) LOADK(k0f, kt + 4)
                STEP(kt, k1f, vfb, kt == ktend)
                kt += 4;
                if (!more) break;
            }
        }
    }

    // partials -> LDS
#pragma unroll
    for (int vn = 0; vn < 4; ++vn)
#pragma unroll
        for (int r = 0; r < 4; ++r)
            OL[w][quad * 4 + r][vn * 16 + ln] = o[vn][r];
    if (quad == 0) { SMm[w][ln] = m; SLl[w][ln] = l; }
    __syncthreads();

    // merge: this wave stores rows w*4+quad (cols ln*4..+3)
    const int row = w * 4 + quad;
    const float mstar = fmaxf(fmaxf(SMm[0][row], SMm[1][row]),
                              fmaxf(SMm[2][row], SMm[3][row]));
    float lstar = 0.f;
    float ox = 0.f, oy = 0.f, oz = 0.f, ow = 0.f;
#pragma unroll
    for (int p = 0; p < 4; ++p) {
        const float sc = EXP2(SMm[p][row] - mstar);
        lstar += SLl[p][row] * sc;
        const float4 ov = *(const float4*)&OL[p][row][ln * 4];
        ox = fmaf(ov.x, sc, ox); oy = fmaf(ov.y, sc, oy);
        oz = fmaf(ov.z, sc, oz); ow = fmaf(ov.w, sc, ow);
    }
    const float inv = 1.f / lstar;
    float4 res; res.x = ox * inv; res.y = oy * inv; res.z = oz * inv; res.w = ow * inv;
    *(float4*)(out + ((size_t)b * T_ + qr0 + row) * 64 + ln * 4) = res;
}

extern "C" void kernel_launch(void* const* d_in, const int* in_sizes, int n_in,
                              void* d_out, int out_size, void* d_ws, size_t ws_size,
                              hipStream_t stream)
{
    const float* x    = (const float*)d_in[0];
    const float* cosp = (const float*)d_in[1];
    const float* sinp = (const float*)d_in[2];
    // d_in[3] = tril: unused (causality structural)
    const float* Wq   = (const float*)d_in[4];
    const float* Wk   = (const float*)d_in[5];
    const float* Wv   = (const float*)d_in[6];
    float* out = (float*)d_out;

    short* Qb = (short*)d_ws;                 // 16384*64 bf16 (pre-scaled)
    short* Kb = Qb + (size_t)NROWS * 64;
    short* Vs = Kb + (size_t)NROWS * 64;      // swizzled V
    short* Wt = Vs + (size_t)NROWS * 64;      // 192*1024 bf16

    wprep_kernel<<<192, 256, 0, stream>>>(Wq, Wk, Wv, Wt);
    qkv_kernel<<<NROWS / 64, 256, 0, stream>>>(x, cosp, sinp, Wt, Qb, Kb, Vs);
    attn_kernel<<<dim3(256, 4), 256, 0, stream>>>(Qb, Kb, Vs, out);
}